// Round 1
// 183.686 us; speedup vs baseline: 1.0499x; 1.0499x over previous
//
#include <hip/hip_runtime.h>
#include <hip/hip_bf16.h>
#include <stdint.h>

#define BATCH 2
#define LQ 2048
#define LK 2048
#define DIM 1024
#define HEADS 8
#define DH 64
#define INNER 512  // HEADS*DH

typedef __attribute__((ext_vector_type(8))) short short8;
typedef __attribute__((ext_vector_type(4))) float f32x4;

__device__ __forceinline__ float bf2f(unsigned short u) {
    union { unsigned int i; float f; } v;
    v.i = ((unsigned int)u) << 16;
    return v.f;
}
__device__ __forceinline__ unsigned short f2bf(float f) {
    __hip_bfloat16 h = __float2bfloat16(f);
    return *reinterpret_cast<unsigned short*>(&h);
}
// raw v_exp_f32 (2^x); __expf would add a *log2e mul we fold into QSCALE
__device__ __forceinline__ float fexp2(float x) {
#if __has_builtin(__builtin_amdgcn_exp2f)
    return __builtin_amdgcn_exp2f(x);
#else
    return __expf(x * 0.69314718056f);
#endif
}
__device__ __forceinline__ void stc(unsigned short* C, size_t i, float v) { C[i] = f2bf(v); }
__device__ __forceinline__ void stc(float* C, size_t i, float v) { C[i] = v; }

// Direct global->LDS DMA, 16B/lane. LDS dest = wave-uniform base + lane*16.
typedef __attribute__((address_space(1))) const unsigned int gu32;
typedef __attribute__((address_space(3))) unsigned int lu32;
__device__ __forceinline__ void gload16(const void* g, void* l) {
    __builtin_amdgcn_global_load_lds((gu32*)g, (lu32*)l, 16, 0, 0);
}

// ---------------------------------------------------------------------------
// prep: fp32->bf16 copies (y=0..5, scalar RNE cvt) + mask bit-pack (y=6),
// one launch. Mask job: 32768 independent wave-tasks, 4 loads in flight.
// ---------------------------------------------------------------------------
__global__ __launch_bounds__(256) void prep(
    const float* __restrict__ x,  const float* __restrict__ y,
    const float* __restrict__ wq, const float* __restrict__ wk,
    const float* __restrict__ wv, const float* __restrict__ wo,
    const float* __restrict__ mask,
    unsigned short* __restrict__ xb,  unsigned short* __restrict__ yb,
    unsigned short* __restrict__ wqb, unsigned short* __restrict__ wkb,
    unsigned short* __restrict__ wvb, unsigned short* __restrict__ wob,
    unsigned long long* __restrict__ mbits)
{
    if (blockIdx.y == 6) {
        const int wid = blockIdx.x * 4 + (threadIdx.x >> 6);   // 4096 waves
        const int lane = threadIdx.x & 63;
        for (int task = wid; task < BATCH * LQ * 8; task += 4096) {
            int row = task >> 3, g = task & 7;
            const float* mp = mask + (size_t)row * LK + g * 256;
            unsigned long long* ob = mbits + (size_t)row * (LK / 64) + g * 4;
            float v0 = mp[0 * 64 + lane];
            float v1 = mp[1 * 64 + lane];
            float v2 = mp[2 * 64 + lane];
            float v3 = mp[3 * 64 + lane];
            unsigned long long b0 = __ballot(v0 > 0.5f);
            unsigned long long b1 = __ballot(v1 > 0.5f);
            unsigned long long b2 = __ballot(v2 > 0.5f);
            unsigned long long b3 = __ballot(v3 > 0.5f);
            if (lane == 0) { ob[0] = b0; ob[1] = b1; ob[2] = b2; ob[3] = b3; }
        }
        return;
    }
    const float* src; unsigned short* dst; int n4;
    switch (blockIdx.y) {
        case 0: src = x;  dst = xb;  n4 = (BATCH * LQ * DIM) / 4; break;
        case 1: src = y;  dst = yb;  n4 = (BATCH * LK * DIM) / 4; break;
        case 2: src = wq; dst = wqb; n4 = (INNER * DIM) / 4; break;
        case 3: src = wk; dst = wkb; n4 = (INNER * DIM) / 4; break;
        case 4: src = wv; dst = wvb; n4 = (INNER * DIM) / 4; break;
        default: src = wo; dst = wob; n4 = (INNER * DIM) / 4; break;
    }
    const int stride = gridDim.x * 256;
    for (int i = blockIdx.x * 256 + threadIdx.x; i < n4; i += stride) {
        float4 f = ((const float4*)src)[i];
        ushort4 u;
        u.x = f2bf(f.x); u.y = f2bf(f.y); u.z = f2bf(f.z); u.w = f2bf(f.w);
        ((ushort4*)dst)[i] = u;
    }
}

// ---------------------------------------------------------------------------
// C = scale * (A[M,K] @ W[N,K]^T), bf16 in, fp32 accum. Tile = (IM*32) x
// (JN*32), BK=64, 4 waves. Swizzled global_load_lds staging (conflict-free
// b128 reads), double-buffered, one barrier/K-tile.
// EPI=0: row-major C. EPI=1: V-transpose epilogue into vt[b][h][d][key].
// ---------------------------------------------------------------------------
template <int IM, int JN, typename TC, int EPI>
__device__ __forceinline__ void gemm_body(
    const unsigned short* __restrict__ A,
    const unsigned short* __restrict__ W,
    TC* __restrict__ C,
    int K, int N, float scale,
    unsigned short* As, unsigned short* Bs)
{
    constexpr int BM = IM * 32;
    constexpr int BN = JN * 32;
    constexpr int ACH = BM * 8;
    constexpr int BCH = BN * 8;
    constexpr int AUS = BM * 64;
    constexpr int BUS = BN * 64;

    const int tid = threadIdx.x;
    const int m0 = blockIdx.x * BM;
    const int n0 = blockIdx.y * BN;
    const int w = tid >> 6, lane = tid & 63;
    const int q4 = lane >> 4, l16 = lane & 15;
    const int wm = (w >> 1) * (IM * 16), wn = (w & 1) * (JN * 16);
    const int sw = l16 & 7;

    f32x4 acc[IM][JN] = {};

#pragma unroll
    for (int i = 0; i < ACH / 256; ++i) {
        int s = tid + i * 256;
        int r = s >> 3, ch = (s & 7) ^ (r & 7);
        gload16(A + (size_t)(m0 + r) * K + ch * 8, As + (size_t)s * 8);
    }
#pragma unroll
    for (int i = 0; i < BCH / 256; ++i) {
        int s = tid + i * 256;
        int r = s >> 3, ch = (s & 7) ^ (r & 7);
        gload16(W + (size_t)(n0 + r) * K + ch * 8, Bs + (size_t)s * 8);
    }
    __syncthreads();

    const int nt = K / 64;
    for (int t = 0; t < nt; ++t) {
        const int curA = (t & 1) * AUS;
        const int curB = (t & 1) * BUS;
        if (t + 1 < nt) {
            int kk = (t + 1) * 64;
            const int nxtA = AUS - curA, nxtB = BUS - curB;
#pragma unroll
            for (int i = 0; i < ACH / 256; ++i) {
                int s = tid + i * 256;
                int r = s >> 3, ch = (s & 7) ^ (r & 7);
                gload16(A + (size_t)(m0 + r) * K + kk + ch * 8, As + nxtA + (size_t)s * 8);
            }
#pragma unroll
            for (int i = 0; i < BCH / 256; ++i) {
                int s = tid + i * 256;
                int r = s >> 3, ch = (s & 7) ^ (r & 7);
                gload16(W + (size_t)(n0 + r) * K + kk + ch * 8, Bs + nxtB + (size_t)s * 8);
            }
        }

#pragma unroll
        for (int ks = 0; ks < 2; ++ks) {
            const int kq = ((ks * 4 + q4) ^ sw) * 8;
            short8 a[IM], b[JN];
#pragma unroll
            for (int i = 0; i < IM; ++i)
                a[i] = *(const short8*)(As + curA + (wm + i * 16 + l16) * 64 + kq);
#pragma unroll
            for (int j = 0; j < JN; ++j)
                b[j] = *(const short8*)(Bs + curB + (wn + j * 16 + l16) * 64 + kq);
#pragma unroll
            for (int i = 0; i < IM; ++i)
#pragma unroll
                for (int j = 0; j < JN; ++j)
                    acc[i][j] = __builtin_amdgcn_mfma_f32_16x16x32_bf16(
                        a[i], b[j], acc[i][j], 0, 0, 0);
        }
        __syncthreads();
    }

    if (EPI == 0) {
        // C/D layout: col = lane&15, row = quad*4 + reg  [m89-verified]
#pragma unroll
        for (int i = 0; i < IM; ++i)
#pragma unroll
            for (int j = 0; j < JN; ++j)
#pragma unroll
                for (int r = 0; r < 4; ++r) {
                    int row = m0 + wm + i * 16 + q4 * 4 + r;
                    int col = n0 + wn + j * 16 + l16;
                    stc(C, (size_t)row * N + col, acc[i][j][r] * scale);
                }
    } else {
        // V-transpose epilogue into vt[((b*H+h)*DH+d)*LK + key].
        constexpr int KW = IM * 16;
        constexpr int DW = JN * 16;
        constexpr int TPS = KW + 8;
        unsigned short* TP = As + w * (DW * TPS);
#pragma unroll
        for (int i = 0; i < IM; ++i)
#pragma unroll
            for (int j = 0; j < JN; ++j) {
                ushort4 u;
                u.x = f2bf(acc[i][j][0]); u.y = f2bf(acc[i][j][1]);
                u.z = f2bf(acc[i][j][2]); u.w = f2bf(acc[i][j][3]);
                *(ushort4*)(TP + (j * 16 + l16) * TPS + i * 16 + q4 * 4) = u;
            }
        const int keyflat = m0 + wm;
        const int bb = keyflat >> 11, key0 = keyflat & (LK - 1);
        const int hh = (n0 + wn) >> 6;
        const int dlow = (n0 + wn) & 63;
        constexpr int RCH = KW / 8;
        constexpr int NCH = DW * RCH;
#pragma unroll
        for (int p = 0; p < NCH / 64; ++p) {
            int c = p * 64 + lane;
            int dl = c / RCH, kc = c % RCH;
            uint4 v = *(const uint4*)(TP + dl * TPS + kc * 8);
            *(uint4*)((unsigned short*)C +
                ((size_t)((bb * HEADS + hh) * DH + dlow + dl)) * LK + key0 + kc * 8) = v;
        }
    }
}

// q scaled by 0.125*log2(e) so attn uses raw v_exp_f32 (2^x) directly.
#define QSCALE 0.18033688011112042f

__global__ __launch_bounds__(256) void proj_qkv(
    const unsigned short* __restrict__ xb, const unsigned short* __restrict__ yb,
    const unsigned short* __restrict__ wqb, const unsigned short* __restrict__ wkb,
    const unsigned short* __restrict__ wvb,
    unsigned short* __restrict__ qb, unsigned short* __restrict__ kb,
    unsigned short* __restrict__ vt)
{
    __shared__ __align__(16) unsigned short As[2 * 128 * 64];
    __shared__ __align__(16) unsigned short Bs[2 * 64 * 64];
    const int z = blockIdx.z;
    const unsigned short* A = (z == 0) ? xb : yb;
    const unsigned short* W = (z == 0) ? wqb : (z == 1) ? wkb : wvb;
    if (z == 2)
        gemm_body<4, 2, unsigned short, 1>(A, W, vt, DIM, INNER, 1.0f, As, Bs);
    else
        gemm_body<4, 2, unsigned short, 0>(A, W, (z == 0) ? qb : kb, DIM, INNER,
                                           (z == 0) ? QSCALE : 1.0f, As, Bs);
}

__global__ __launch_bounds__(256) void gemm_out(
    const unsigned short* __restrict__ A,
    const unsigned short* __restrict__ W,
    float* __restrict__ C)
{
    __shared__ __align__(16) unsigned short As[2 * 128 * 64];
    __shared__ __align__(16) unsigned short Bs[2 * 64 * 64];
    gemm_body<4, 2, float, 0>(A, W, C, INNER, DIM, 1.0f, As, Bs);
}

// ---------------------------------------------------------------------------
// Flash attention v2: occupancy restructure.
// 512 threads / 8 waves per block; waves 0..3 own the four 16-row q-groups
// for EVEN key tiles, waves 4..7 the same rows for ODD tiles (no-max softmax
// => exact partial sums, combined through LDS at the end). K/V are 4-slot
// ring buffers (pair double-buffering, ONE barrier per 2 tiles). P tile is
// per-wave 16x64, stride-64 with XOR chunk swizzle (chunk ^= row&7) so the
// b128 reads stay at the 8-cycle LDS floor without the +8 pad.
// LDS = 32K (K) + 32K (V) + 16K (P) = 81920 B -> exactly 2 blocks/CU
// -> 16 waves/CU = 4 waves/SIMD (2x the previous occupancy).
// ---------------------------------------------------------------------------
#define AT_SLOT (64 * 64)

__global__ __launch_bounds__(512, 4) void attn_mfma(
    const unsigned short* __restrict__ Q,
    const unsigned short* __restrict__ Kb,
    const unsigned short* __restrict__ Vt,
    const unsigned long long* __restrict__ Mb,
    unsigned short* __restrict__ O)
{
    __shared__ __align__(16) unsigned short Ks[4 * AT_SLOT];   // 32 KB
    __shared__ __align__(16) unsigned short Vs[4 * AT_SLOT];   // 32 KB
    __shared__ __align__(16) unsigned short Ps[8 * 16 * 64];   // 16 KB swizzled

    const int tid = threadIdx.x;
    const int q0 = blockIdx.x * 64;
    const int h = blockIdx.y, b = blockIdx.z;
    const int w = tid >> 6, lane = tid & 63;
    const int g = w & 3;           // q-row group (16 rows)
    const int par = w >> 2;        // key-tile parity this wave computes
    const int q4 = lane >> 4, l16 = lane & 15;
    const int sw = l16 & 7;

    short8 qf[2];
    {
        const unsigned short* qp =
            Q + (size_t)(b * LQ + q0 + g * 16 + l16) * INNER + h * DH + q4 * 8;
        qf[0] = *(const short8*)(qp);
        qf[1] = *(const short8*)(qp + 32);
    }

    f32x4 o[4] = {};
    float lacc[4] = {0.f, 0.f, 0.f, 0.f};

    const unsigned short* kbase = Kb + (size_t)(b * LK) * INNER + h * DH;
    const unsigned short* vbase = Vt + (size_t)((b * HEADS + h) * DH) * LK;
    const unsigned long long* mrow =
        Mb + (size_t)(b * LQ + q0 + g * 16 + q4 * 4) * (LK / 64);

    // per-thread staging coords: 512 threads stage one 64x64 tile per gload16
    const int rr = tid >> 3;
    const int ch = (tid & 7) ^ (rr & 7);

    // prologue: tiles 0,1 -> slots 0,1
#pragma unroll
    for (int tn = 0; tn < 2; ++tn) {
        gload16(kbase + (size_t)(tn * 64 + rr) * INNER + ch * 8,
                Ks + tn * AT_SLOT + (size_t)tid * 8);
        gload16(vbase + (size_t)rr * LK + tn * 64 + ch * 8,
                Vs + tn * AT_SLOT + (size_t)tid * 8);
    }
    __syncthreads();

    const int NR = LK / 128;   // 16 rounds, 2 tiles each
    for (int rd = 0; rd < NR; ++rd) {
        if (rd + 1 < NR) {
#pragma unroll
            for (int i = 0; i < 2; ++i) {
                const int tn = 2 * rd + 2 + i;
                const int sl = tn & 3;
                gload16(kbase + (size_t)(tn * 64 + rr) * INNER + ch * 8,
                        Ks + sl * AT_SLOT + (size_t)tid * 8);
                gload16(vbase + (size_t)rr * LK + tn * 64 + ch * 8,
                        Vs + sl * AT_SLOT + (size_t)tid * 8);
            }
        }
        const int t = 2 * rd + par;
        const int cur = (t & 3) * AT_SLOT;

        // ---- S = Q K^T (swizzled kf reads) ----
        f32x4 s[4];
#pragma unroll
        for (int j = 0; j < 4; ++j) {
            s[j] = f32x4{0.f, 0.f, 0.f, 0.f};
#pragma unroll
            for (int ks = 0; ks < 2; ++ks) {
                short8 kf = *(const short8*)(Ks + cur + (j * 16 + l16) * 64
                                             + (((ks * 4 + q4) ^ sw) * 8));
                s[j] = __builtin_amdgcn_mfma_f32_16x16x32_bf16(qf[ks], kf, s[j], 0, 0, 0);
            }
        }

        // ---- p = masked ? 0 : 2^s  (log2e folded into q) ----
#pragma unroll
        for (int r2 = 0; r2 < 4; ++r2) {
            unsigned long long bits = mrow[(size_t)r2 * (LK / 64) + t];
#pragma unroll
            for (int j = 0; j < 4; ++j) {
                float e = fexp2(s[j][r2]);
                float pe = ((bits >> (j * 16 + l16)) & 1ull) ? 0.f : e;
                s[j][r2] = pe;
                lacc[r2] += pe;
            }
        }

        // ---- P (C-layout) -> per-wave swizzled LDS (no barrier; in-order DS)
        unsigned short* Pw = Ps + w * 1024;
#pragma unroll
        for (int j = 0; j < 4; ++j)
#pragma unroll
            for (int r2 = 0; r2 < 4; ++r2) {
                const int row = q4 * 4 + r2;
                Pw[row * 64 + (((j * 2 + (l16 >> 3)) ^ (row & 7)) << 3) + (l16 & 7)]
                    = f2bf(s[j][r2]);
            }

        // ---- O += P V (swizzled pf/vf reads) ----
#pragma unroll
        for (int ks = 0; ks < 2; ++ks) {
            short8 pf = *(const short8*)(Pw + l16 * 64 + (((ks * 4 + q4) ^ sw) << 3));
#pragma unroll
            for (int dd = 0; dd < 4; ++dd) {
                short8 vf = *(const short8*)(Vs + cur + (dd * 16 + l16) * 64
                                             + (((ks * 4 + q4) ^ sw) * 8));
                o[dd] = __builtin_amdgcn_mfma_f32_16x16x32_bf16(pf, vf, o[dd], 0, 0, 0);
            }
        }
        __syncthreads();
    }

    // ---- parity combine (exact: no-max softmax partial sums add) ----
    // Ks is dead; reuse as f32 exchange. stride 21 floats -> conflict-free.
    float* xch = (float*)Ks;
    if (par) {
        float* d = xch + (size_t)(g * 64 + lane) * 21;
#pragma unroll
        for (int dd = 0; dd < 4; ++dd)
#pragma unroll
            for (int r2 = 0; r2 < 4; ++r2) d[dd * 4 + r2] = o[dd][r2];
#pragma unroll
        for (int r2 = 0; r2 < 4; ++r2) d[16 + r2] = lacc[r2];
    }
    __syncthreads();
    if (!par) {
        const float* d = xch + (size_t)(g * 64 + lane) * 21;
#pragma unroll
        for (int dd = 0; dd < 4; ++dd)
#pragma unroll
            for (int r2 = 0; r2 < 4; ++r2) o[dd][r2] += d[dd * 4 + r2];
#pragma unroll
        for (int r2 = 0; r2 < 4; ++r2) lacc[r2] += d[16 + r2];

        // reduce l across the 16 key-lanes, then store
#pragma unroll
        for (int off = 1; off < 16; off <<= 1)
#pragma unroll
            for (int r2 = 0; r2 < 4; ++r2)
                lacc[r2] += __shfl_xor(lacc[r2], off);
        float inv[4];
#pragma unroll
        for (int r2 = 0; r2 < 4; ++r2) inv[r2] = 1.0f / lacc[r2];

#pragma unroll
        for (int dd = 0; dd < 4; ++dd)
#pragma unroll
            for (int r2 = 0; r2 < 4; ++r2) {
                int qrow = b * LQ + q0 + g * 16 + q4 * 4 + r2;
                int col = h * DH + dd * 16 + l16;
                O[(size_t)qrow * INNER + col] = f2bf(o[dd][r2] * inv[r2]);
            }
    }
}

extern "C" void kernel_launch(void* const* d_in, const int* in_sizes, int n_in,
                              void* d_out, int out_size, void* d_ws, size_t ws_size,
                              hipStream_t stream) {
    const float* x    = (const float*)d_in[0];
    const float* y    = (const float*)d_in[1];
    const float* mask = (const float*)d_in[2];
    const float* Wq   = (const float*)d_in[3];
    const float* Wk   = (const float*)d_in[4];
    const float* Wv   = (const float*)d_in[5];
    const float* Wo   = (const float*)d_in[6];
    float* out = (float*)d_out;

    const size_t NX = (size_t)BATCH * LQ * DIM;    // 4.19M
    const size_t NS = (size_t)BATCH * LQ * INNER;  // 2.10M
    const size_t NW = (size_t)INNER * DIM;         // 0.52M
    unsigned short* xb  = (unsigned short*)d_ws;
    unsigned short* yb  = xb + NX;
    unsigned short* qb  = yb + NX;
    unsigned short* kb  = qb + NS;
    unsigned short* vt  = kb + NS;
    unsigned short* wqb = vt + NS;
    unsigned short* wkb = wqb + NW;
    unsigned short* wvb = wkb + NW;
    unsigned short* wob = wvb + NW;
    unsigned long long* mbits = (unsigned long long*)(wob + NW);
    unsigned short* ao  = xb;   // xb dead after proj
    // ws: 33.8 MB bf16 + 1 MB bits

    dim3 blk(256);
    prep<<<dim3(1024, 7), blk, 0, stream>>>(
        x, y, Wq, Wk, Wv, Wo, mask, xb, yb, wqb, wkb, wvb, wob, mbits);
    proj_qkv<<<dim3(4096 / 128, INNER / 64, 3), blk, 0, stream>>>(
        xb, yb, wqb, wkb, wvb, qb, kb, vt);
    attn_mfma<<<dim3(LQ / 64, HEADS, BATCH), dim3(512), 0, stream>>>(
        qb, kb, vt, mbits, ao);
    gemm_out<<<dim3(4096 / 128, DIM / 64), blk, 0, stream>>>(ao, wob, out);
}

// Round 3
// 179.398 us; speedup vs baseline: 1.0750x; 1.0239x over previous
//
#include <hip/hip_runtime.h>
#include <hip/hip_bf16.h>
#include <stdint.h>

#define BATCH 2
#define LQ 2048
#define LK 2048
#define DIM 1024
#define HEADS 8
#define DH 64
#define INNER 512  // HEADS*DH

typedef __attribute__((ext_vector_type(8))) short short8;
typedef __attribute__((ext_vector_type(4))) float f32x4;

__device__ __forceinline__ float bf2f(unsigned short u) {
    union { unsigned int i; float f; } v;
    v.i = ((unsigned int)u) << 16;
    return v.f;
}
__device__ __forceinline__ unsigned short f2bf(float f) {
    __hip_bfloat16 h = __float2bfloat16(f);
    return *reinterpret_cast<unsigned short*>(&h);
}
// raw v_exp_f32 (2^x); __expf would add a *log2e mul we fold into QSCALE
__device__ __forceinline__ float fexp2(float x) {
#if __has_builtin(__builtin_amdgcn_exp2f)
    return __builtin_amdgcn_exp2f(x);
#else
    return __expf(x * 0.69314718056f);
#endif
}
__device__ __forceinline__ void stc(unsigned short* C, size_t i, float v) { C[i] = f2bf(v); }
__device__ __forceinline__ void stc(float* C, size_t i, float v) { C[i] = v; }

// packed f32x2 -> bf16x2 (RNE), single instruction (T12 recipe; no builtin)
__device__ __forceinline__ unsigned cvtpk_bf16(float lo, float hi) {
    unsigned r;
    asm("v_cvt_pk_bf16_f32 %0, %1, %2" : "=v"(r) : "v"(lo), "v"(hi));
    return r;
}
// permlane swaps (gfx950): 32-swap: dst.hi32 <-> src.lo32 ; 16-swap: odd
// 16-rows of dst <-> even 16-rows of src.
__device__ __forceinline__ void perm32swap(unsigned& a, unsigned& b) {
#if __has_builtin(__builtin_amdgcn_permlane32_swap)
    auto r = __builtin_amdgcn_permlane32_swap(a, b, false, false);
    a = r[0]; b = r[1];
#else
    asm volatile("v_permlane32_swap_b32 %0, %1" : "+v"(a), "+v"(b));
#endif
}
__device__ __forceinline__ void perm16swap(unsigned& a, unsigned& b) {
#if __has_builtin(__builtin_amdgcn_permlane16_swap)
    auto r = __builtin_amdgcn_permlane16_swap(a, b, false, false);
    a = r[0]; b = r[1];
#else
    asm volatile("v_permlane16_swap_b32 %0, %1" : "+v"(a), "+v"(b));
#endif
}

// Direct global->LDS DMA, 16B/lane. LDS dest = wave-uniform base + lane*16.
typedef __attribute__((address_space(1))) const unsigned int gu32;
typedef __attribute__((address_space(3))) unsigned int lu32;
__device__ __forceinline__ void gload16(const void* g, void* l) {
    __builtin_amdgcn_global_load_lds((gu32*)g, (lu32*)l, 16, 0, 0);
}

// ---------------------------------------------------------------------------
// prep: fp32->bf16 copies (y=0..5, scalar RNE cvt) + mask bit-pack (y=6),
// one launch. Mask job: 32768 independent wave-tasks, 4 loads in flight.
// ---------------------------------------------------------------------------
__global__ __launch_bounds__(256) void prep(
    const float* __restrict__ x,  const float* __restrict__ y,
    const float* __restrict__ wq, const float* __restrict__ wk,
    const float* __restrict__ wv, const float* __restrict__ wo,
    const float* __restrict__ mask,
    unsigned short* __restrict__ xb,  unsigned short* __restrict__ yb,
    unsigned short* __restrict__ wqb, unsigned short* __restrict__ wkb,
    unsigned short* __restrict__ wvb, unsigned short* __restrict__ wob,
    unsigned long long* __restrict__ mbits)
{
    if (blockIdx.y == 6) {
        const int wid = blockIdx.x * 4 + (threadIdx.x >> 6);   // 4096 waves
        const int lane = threadIdx.x & 63;
        for (int task = wid; task < BATCH * LQ * 8; task += 4096) {
            int row = task >> 3, g = task & 7;
            const float* mp = mask + (size_t)row * LK + g * 256;
            unsigned long long* ob = mbits + (size_t)row * (LK / 64) + g * 4;
            float v0 = mp[0 * 64 + lane];
            float v1 = mp[1 * 64 + lane];
            float v2 = mp[2 * 64 + lane];
            float v3 = mp[3 * 64 + lane];
            unsigned long long b0 = __ballot(v0 > 0.5f);
            unsigned long long b1 = __ballot(v1 > 0.5f);
            unsigned long long b2 = __ballot(v2 > 0.5f);
            unsigned long long b3 = __ballot(v3 > 0.5f);
            if (lane == 0) { ob[0] = b0; ob[1] = b1; ob[2] = b2; ob[3] = b3; }
        }
        return;
    }
    const float* src; unsigned short* dst; int n4;
    switch (blockIdx.y) {
        case 0: src = x;  dst = xb;  n4 = (BATCH * LQ * DIM) / 4; break;
        case 1: src = y;  dst = yb;  n4 = (BATCH * LK * DIM) / 4; break;
        case 2: src = wq; dst = wqb; n4 = (INNER * DIM) / 4; break;
        case 3: src = wk; dst = wkb; n4 = (INNER * DIM) / 4; break;
        case 4: src = wv; dst = wvb; n4 = (INNER * DIM) / 4; break;
        default: src = wo; dst = wob; n4 = (INNER * DIM) / 4; break;
    }
    const int stride = gridDim.x * 256;
    for (int i = blockIdx.x * 256 + threadIdx.x; i < n4; i += stride) {
        float4 f = ((const float4*)src)[i];
        ushort4 u;
        u.x = f2bf(f.x); u.y = f2bf(f.y); u.z = f2bf(f.z); u.w = f2bf(f.w);
        ((ushort4*)dst)[i] = u;
    }
}

// ---------------------------------------------------------------------------
// C = scale * (A[M,K] @ W[N,K]^T), bf16 in, fp32 accum. Tile = (IM*32) x
// (JN*32), BK=64, 4 waves. Swizzled global_load_lds staging (conflict-free
// b128 reads), double-buffered, one barrier/K-tile.
// EPI=0: row-major C. EPI=1: V-transpose epilogue into vt[b][h][d][key].
// ---------------------------------------------------------------------------
template <int IM, int JN, typename TC, int EPI>
__device__ __forceinline__ void gemm_body(
    const unsigned short* __restrict__ A,
    const unsigned short* __restrict__ W,
    TC* __restrict__ C,
    int K, int N, float scale,
    unsigned short* As, unsigned short* Bs)
{
    constexpr int BM = IM * 32;
    constexpr int BN = JN * 32;
    constexpr int ACH = BM * 8;
    constexpr int BCH = BN * 8;
    constexpr int AUS = BM * 64;
    constexpr int BUS = BN * 64;

    const int tid = threadIdx.x;
    const int m0 = blockIdx.x * BM;
    const int n0 = blockIdx.y * BN;
    const int w = tid >> 6, lane = tid & 63;
    const int q4 = lane >> 4, l16 = lane & 15;
    const int wm = (w >> 1) * (IM * 16), wn = (w & 1) * (JN * 16);
    const int sw = l16 & 7;

    f32x4 acc[IM][JN] = {};

#pragma unroll
    for (int i = 0; i < ACH / 256; ++i) {
        int s = tid + i * 256;
        int r = s >> 3, ch = (s & 7) ^ (r & 7);
        gload16(A + (size_t)(m0 + r) * K + ch * 8, As + (size_t)s * 8);
    }
#pragma unroll
    for (int i = 0; i < BCH / 256; ++i) {
        int s = tid + i * 256;
        int r = s >> 3, ch = (s & 7) ^ (r & 7);
        gload16(W + (size_t)(n0 + r) * K + ch * 8, Bs + (size_t)s * 8);
    }
    __syncthreads();

    const int nt = K / 64;
    for (int t = 0; t < nt; ++t) {
        const int curA = (t & 1) * AUS;
        const int curB = (t & 1) * BUS;
        if (t + 1 < nt) {
            int kk = (t + 1) * 64;
            const int nxtA = AUS - curA, nxtB = BUS - curB;
#pragma unroll
            for (int i = 0; i < ACH / 256; ++i) {
                int s = tid + i * 256;
                int r = s >> 3, ch = (s & 7) ^ (r & 7);
                gload16(A + (size_t)(m0 + r) * K + kk + ch * 8, As + nxtA + (size_t)s * 8);
            }
#pragma unroll
            for (int i = 0; i < BCH / 256; ++i) {
                int s = tid + i * 256;
                int r = s >> 3, ch = (s & 7) ^ (r & 7);
                gload16(W + (size_t)(n0 + r) * K + kk + ch * 8, Bs + nxtB + (size_t)s * 8);
            }
        }

#pragma unroll
        for (int ks = 0; ks < 2; ++ks) {
            const int kq = ((ks * 4 + q4) ^ sw) * 8;
            short8 a[IM], b[JN];
#pragma unroll
            for (int i = 0; i < IM; ++i)
                a[i] = *(const short8*)(As + curA + (wm + i * 16 + l16) * 64 + kq);
#pragma unroll
            for (int j = 0; j < JN; ++j)
                b[j] = *(const short8*)(Bs + curB + (wn + j * 16 + l16) * 64 + kq);
#pragma unroll
            for (int i = 0; i < IM; ++i)
#pragma unroll
                for (int j = 0; j < JN; ++j)
                    acc[i][j] = __builtin_amdgcn_mfma_f32_16x16x32_bf16(
                        a[i], b[j], acc[i][j], 0, 0, 0);
        }
        __syncthreads();
    }

    if (EPI == 0) {
        // C/D layout: col = lane&15, row = quad*4 + reg  [m89-verified]
#pragma unroll
    for (int i = 0; i < IM; ++i)
#pragma unroll
            for (int j = 0; j < JN; ++j)
#pragma unroll
                for (int r = 0; r < 4; ++r) {
                    int row = m0 + wm + i * 16 + q4 * 4 + r;
                    int col = n0 + wn + j * 16 + l16;
                    stc(C, (size_t)row * N + col, acc[i][j][r] * scale);
                }
    } else {
        // V-transpose epilogue into vt[((b*H+h)*DH+d)*LK + key].
        constexpr int KW = IM * 16;
        constexpr int DW = JN * 16;
        constexpr int TPS = KW + 8;
        unsigned short* TP = As + w * (DW * TPS);
#pragma unroll
        for (int i = 0; i < IM; ++i)
#pragma unroll
            for (int j = 0; j < JN; ++j) {
                ushort4 u;
                u.x = f2bf(acc[i][j][0]); u.y = f2bf(acc[i][j][1]);
                u.z = f2bf(acc[i][j][2]); u.w = f2bf(acc[i][j][3]);
                *(ushort4*)(TP + (j * 16 + l16) * TPS + i * 16 + q4 * 4) = u;
            }
        const int keyflat = m0 + wm;
        const int bb = keyflat >> 11, key0 = keyflat & (LK - 1);
        const int hh = (n0 + wn) >> 6;
        const int dlow = (n0 + wn) & 63;
        constexpr int RCH = KW / 8;
        constexpr int NCH = DW * RCH;
#pragma unroll
        for (int p = 0; p < NCH / 64; ++p) {
            int c = p * 64 + lane;
            int dl = c / RCH, kc = c % RCH;
            uint4 v = *(const uint4*)(TP + dl * TPS + kc * 8);
            *(uint4*)((unsigned short*)C +
                ((size_t)((bb * HEADS + hh) * DH + dlow + dl)) * LK + key0 + kc * 8) = v;
        }
    }
}

// q scaled by 0.125*log2(e) so attn uses raw v_exp_f32 (2^x) directly.
#define QSCALE 0.18033688011112042f

__global__ __launch_bounds__(256) void proj_qkv(
    const unsigned short* __restrict__ xb, const unsigned short* __restrict__ yb,
    const unsigned short* __restrict__ wqb, const unsigned short* __restrict__ wkb,
    const unsigned short* __restrict__ wvb,
    unsigned short* __restrict__ qb, unsigned short* __restrict__ kb,
    unsigned short* __restrict__ vt)
{
    __shared__ __align__(16) unsigned short As[2 * 128 * 64];
    __shared__ __align__(16) unsigned short Bs[2 * 64 * 64];
    const int z = blockIdx.z;
    const unsigned short* A = (z == 0) ? xb : yb;
    const unsigned short* W = (z == 0) ? wqb : (z == 1) ? wkb : wvb;
    if (z == 2)
        gemm_body<4, 2, unsigned short, 1>(A, W, vt, DIM, INNER, 1.0f, As, Bs);
    else
        gemm_body<4, 2, unsigned short, 0>(A, W, (z == 0) ? qb : kb, DIM, INNER,
                                           (z == 0) ? QSCALE : 1.0f, As, Bs);
}

__global__ __launch_bounds__(256) void gemm_out(
    const unsigned short* __restrict__ A,
    const unsigned short* __restrict__ W,
    float* __restrict__ C)
{
    __shared__ __align__(16) unsigned short As[2 * 128 * 64];
    __shared__ __align__(16) unsigned short Bs[2 * 64 * 64];
    gemm_body<4, 2, float, 0>(A, W, C, INNER, DIM, 1.0f, As, Bs);
}

// ---------------------------------------------------------------------------
// Flash attention v3: in-register P path (T12 swapped-operand softmax).
// S^T = mfma(K, Q): lane(q4,l16) holds P[key=16j+4*q4+r][q=l16]. PV is
// O^T = mfma(V^T, P^T); V^T is exactly what vt stages, so vf reads are
// unchanged. P^T B-frag built in-register: 8x v_cvt_pk_bf16_f32 + per-ks
// {permlane32_swap; permlane16_swap} on (w[j0],w[j1]) pairs:
//   32-swap: [A0|A1|A2|A3],[B0|B1|B2|B3] -> [A0|A1|B0|B1],[A2|A3|B2|B3]
//   16-swap: -> [A0|A2|B0|B2] (=keys {0,1},{4,5} slot), [A1|A3|B1|B3]
// Removes the P LDS round-trip (16 ds_write_b16 + 2 ds_read_b128 + in-order
// DS drain), 3 of 4 mask loads, and makes the O store 4x8B contiguous.
// Wave split unchanged: 8 waves, par=tile parity, exact partial sums.
// LDS = 32K (K) + 32K (V) = 65536 B.
// ---------------------------------------------------------------------------
#define AT_SLOT (64 * 64)

__global__ __launch_bounds__(512, 4) void attn_mfma(
    const unsigned short* __restrict__ Q,
    const unsigned short* __restrict__ Kb,
    const unsigned short* __restrict__ Vt,
    const unsigned long long* __restrict__ Mb,
    unsigned short* __restrict__ O)
{
    __shared__ __align__(16) unsigned short Ks[4 * AT_SLOT];   // 32 KB
    __shared__ __align__(16) unsigned short Vs[4 * AT_SLOT];   // 32 KB

    const int tid = threadIdx.x;
    const int q0 = blockIdx.x * 64;
    const int h = blockIdx.y, b = blockIdx.z;
    const int w = tid >> 6, lane = tid & 63;
    const int g = w & 3;           // q-row group (16 rows)
    const int par = w >> 2;        // key-tile parity this wave computes
    const int q4 = lane >> 4, l16 = lane & 15;
    const int sw = l16 & 7;

    // Q as B-operand fragment: col q = l16, k-chunk = q4 (same bytes as v2)
    short8 qf[2];
    {
        const unsigned short* qp =
            Q + (size_t)(b * LQ + q0 + g * 16 + l16) * INNER + h * DH + q4 * 8;
        qf[0] = *(const short8*)(qp);
        qf[1] = *(const short8*)(qp + 32);
    }

    f32x4 o[4] = {};
    float lacc = 0.f;

    const unsigned short* kbase = Kb + (size_t)(b * LK) * INNER + h * DH;
    const unsigned short* vbase = Vt + (size_t)((b * HEADS + h) * DH) * LK;
    // one mask row per lane now: q = l16
    const unsigned long long* mrow =
        Mb + (size_t)(b * LQ + q0 + g * 16 + l16) * (LK / 64);

    // per-thread staging coords: 512 threads stage one 64x64 tile per gload16
    const int rr = tid >> 3;
    const int ch = (tid & 7) ^ (rr & 7);

    // prologue: tiles 0,1 -> slots 0,1
#pragma unroll
    for (int tn = 0; tn < 2; ++tn) {
        gload16(kbase + (size_t)(tn * 64 + rr) * INNER + ch * 8,
                Ks + tn * AT_SLOT + (size_t)tid * 8);
        gload16(vbase + (size_t)rr * LK + tn * 64 + ch * 8,
                Vs + tn * AT_SLOT + (size_t)tid * 8);
    }
    __syncthreads();

    const int NR = LK / 128;   // 16 rounds, 2 tiles each
    for (int rd = 0; rd < NR; ++rd) {
        if (rd + 1 < NR) {
#pragma unroll
            for (int i = 0; i < 2; ++i) {
                const int tn = 2 * rd + 2 + i;
                const int sl = tn & 3;
                gload16(kbase + (size_t)(tn * 64 + rr) * INNER + ch * 8,
                        Ks + sl * AT_SLOT + (size_t)tid * 8);
                gload16(vbase + (size_t)rr * LK + tn * 64 + ch * 8,
                        Vs + sl * AT_SLOT + (size_t)tid * 8);
            }
        }
        const int t = 2 * rd + par;
        const int cur = (t & 3) * AT_SLOT;

        // ---- S^T = K Q^T (A = K rows, B = Q) ----
        f32x4 s[4];
#pragma unroll
        for (int j = 0; j < 4; ++j) {
            s[j] = f32x4{0.f, 0.f, 0.f, 0.f};
#pragma unroll
            for (int ks = 0; ks < 2; ++ks) {
                short8 kf = *(const short8*)(Ks + cur + (j * 16 + l16) * 64
                                             + (((ks * 4 + q4) ^ sw) * 8));
                s[j] = __builtin_amdgcn_mfma_f32_16x16x32_bf16(kf, qf[ks], s[j], 0, 0, 0);
            }
        }

        // ---- p = masked ? 0 : 2^s ; pack to bf16 pairs in-register ----
        // lane needs key bits {16j + 4*q4 + r}: shift out 4*q4, then nibbles.
        unsigned long long bsh = mrow[t] >> (q4 * 4);
        unsigned pk[8];
#pragma unroll
        for (int j = 0; j < 4; ++j) {
            unsigned nib = (unsigned)(bsh >> (16 * j)) & 0xFu;
            float p0 = (nib & 1u) ? 0.f : fexp2(s[j][0]);
            float p1 = (nib & 2u) ? 0.f : fexp2(s[j][1]);
            float p2 = (nib & 4u) ? 0.f : fexp2(s[j][2]);
            float p3 = (nib & 8u) ? 0.f : fexp2(s[j][3]);
            lacc += (p0 + p1) + (p2 + p3);
            pk[2 * j]     = cvtpk_bf16(p0, p1);
            pk[2 * j + 1] = cvtpk_bf16(p2, p3);
        }

        // ---- P^T B-frag via permlane (no LDS) ----
        short8 pf[2];
#pragma unroll
        for (int ks = 0; ks < 2; ++ks) {
            unsigned a0 = pk[4 * ks + 0], b0 = pk[4 * ks + 2];  // w0[j0], w0[j1]
            unsigned a1 = pk[4 * ks + 1], b1 = pk[4 * ks + 3];  // w1[j0], w1[j1]
            perm32swap(a0, b0); perm16swap(a0, b0);  // a0 = keys{0,1}, b0 = keys{4,5}
            perm32swap(a1, b1); perm16swap(a1, b1);  // a1 = keys{2,3}, b1 = keys{6,7}
            union { unsigned u[4]; short8 s8; } up;
            up.u[0] = a0; up.u[1] = a1; up.u[2] = b0; up.u[3] = b1;
            pf[ks] = up.s8;
        }

        // ---- O^T += V^T P^T (vf reads unchanged) ----
#pragma unroll
        for (int ks = 0; ks < 2; ++ks) {
#pragma unroll
            for (int dd = 0; dd < 4; ++dd) {
                short8 vf = *(const short8*)(Vs + cur + (dd * 16 + l16) * 64
                                             + (((ks * 4 + q4) ^ sw) * 8));
                o[dd] = __builtin_amdgcn_mfma_f32_16x16x32_bf16(vf, pf[ks], o[dd], 0, 0, 0);
            }
        }
        __syncthreads();
    }

    // ---- parity combine (exact: no-max softmax partial sums add) ----
    // Ks is dead; reuse as f32 exchange. 17 floats/lane, odd stride => 2-way.
    float* xch = (float*)Ks;
    if (par) {
        float* d = xch + (size_t)(g * 64 + lane) * 17;
#pragma unroll
        for (int dd = 0; dd < 4; ++dd)
#pragma unroll
            for (int r2 = 0; r2 < 4; ++r2) d[dd * 4 + r2] = o[dd][r2];
        d[16] = lacc;
    }
    __syncthreads();
    if (!par) {
        const float* d = xch + (size_t)(g * 64 + lane) * 17;
#pragma unroll
        for (int dd = 0; dd < 4; ++dd)
#pragma unroll
            for (int r2 = 0; r2 < 4; ++r2) o[dd][r2] += d[dd * 4 + r2];
        lacc += d[16];

        // reduce l across the 4 q4 groups (keys were split across q4)
        lacc += __shfl_xor(lacc, 16);
        lacc += __shfl_xor(lacc, 32);
        const float inv = 1.0f / lacc;

        // O^T layout: q = l16 (one row per lane), d = dd*16 + q4*4 + r
        unsigned short* orow =
            O + (size_t)(b * LQ + q0 + g * 16 + l16) * INNER + h * DH + q4 * 4;
#pragma unroll
        for (int dd = 0; dd < 4; ++dd) {
            ushort4 u;
            u.x = f2bf(o[dd][0] * inv); u.y = f2bf(o[dd][1] * inv);
            u.z = f2bf(o[dd][2] * inv); u.w = f2bf(o[dd][3] * inv);
            *(ushort4*)(orow + dd * 16) = u;
        }
    }
}

extern "C" void kernel_launch(void* const* d_in, const int* in_sizes, int n_in,
                              void* d_out, int out_size, void* d_ws, size_t ws_size,
                              hipStream_t stream) {
    const float* x    = (const float*)d_in[0];
    const float* y    = (const float*)d_in[1];
    const float* mask = (const float*)d_in[2];
    const float* Wq   = (const float*)d_in[3];
    const float* Wk   = (const float*)d_in[4];
    const float* Wv   = (const float*)d_in[5];
    const float* Wo   = (const float*)d_in[6];
    float* out = (float*)d_out;

    const size_t NX = (size_t)BATCH * LQ * DIM;    // 4.19M
    const size_t NS = (size_t)BATCH * LQ * INNER;  // 2.10M
    const size_t NW = (size_t)INNER * DIM;         // 0.52M
    unsigned short* xb  = (unsigned short*)d_ws;
    unsigned short* yb  = xb + NX;
    unsigned short* qb  = yb + NX;
    unsigned short* kb  = qb + NS;
    unsigned short* vt  = kb + NS;
    unsigned short* wqb = vt + NS;
    unsigned short* wkb = wqb + NW;
    unsigned short* wvb = wkb + NW;
    unsigned short* wob = wvb + NW;
    unsigned long long* mbits = (unsigned long long*)(wob + NW);
    unsigned short* ao  = xb;   // xb dead after proj
    // ws: 33.8 MB bf16 + 1 MB bits

    dim3 blk(256);
    prep<<<dim3(1024, 7), blk, 0, stream>>>(
        x, y, Wq, Wk, Wv, Wo, mask, xb, yb, wqb, wkb, wvb, wob, mbits);
    proj_qkv<<<dim3(4096 / 128, INNER / 64, 3), blk, 0, stream>>>(
        xb, yb, wqb, wkb, wvb, qb, kb, vt);
    attn_mfma<<<dim3(LQ / 64, HEADS, BATCH), dim3(512), 0, stream>>>(
        qb, kb, vt, mbits, ao);
    gemm_out<<<dim3(4096 / 128, DIM / 64), blk, 0, stream>>>(ao, wob, out);
}

// Round 4
// 171.788 us; speedup vs baseline: 1.1227x; 1.0443x over previous
//
#include <hip/hip_runtime.h>
#include <hip/hip_bf16.h>
#include <stdint.h>

#define BATCH 2
#define LQ 2048
#define LK 2048
#define DIM 1024
#define HEADS 8
#define DH 64
#define INNER 512  // HEADS*DH

typedef __attribute__((ext_vector_type(8))) short short8;
typedef __attribute__((ext_vector_type(4))) float f32x4;

__device__ __forceinline__ float bf2f(unsigned short u) {
    union { unsigned int i; float f; } v;
    v.i = ((unsigned int)u) << 16;
    return v.f;
}
__device__ __forceinline__ unsigned short f2bf(float f) {
    __hip_bfloat16 h = __float2bfloat16(f);
    return *reinterpret_cast<unsigned short*>(&h);
}
// raw v_exp_f32 (2^x); __expf would add a *log2e mul we fold into QSCALE
__device__ __forceinline__ float fexp2(float x) {
#if __has_builtin(__builtin_amdgcn_exp2f)
    return __builtin_amdgcn_exp2f(x);
#else
    return __expf(x * 0.69314718056f);
#endif
}
__device__ __forceinline__ void stc(unsigned short* C, size_t i, float v) { C[i] = f2bf(v); }
__device__ __forceinline__ void stc(float* C, size_t i, float v) { C[i] = v; }

// packed f32x2 -> bf16x2 (RNE), single instruction (T12 recipe; no builtin)
__device__ __forceinline__ unsigned cvtpk_bf16(float lo, float hi) {
    unsigned r;
    asm("v_cvt_pk_bf16_f32 %0, %1, %2" : "=v"(r) : "v"(lo), "v"(hi));
    return r;
}
// permlane swaps (gfx950): 32-swap: dst.hi32 <-> src.lo32 ; 16-swap: odd
// 16-rows of dst <-> even 16-rows of src.
__device__ __forceinline__ void perm32swap(unsigned& a, unsigned& b) {
#if __has_builtin(__builtin_amdgcn_permlane32_swap)
    auto r = __builtin_amdgcn_permlane32_swap(a, b, false, false);
    a = r[0]; b = r[1];
#else
    asm volatile("v_permlane32_swap_b32 %0, %1" : "+v"(a), "+v"(b));
#endif
}
__device__ __forceinline__ void perm16swap(unsigned& a, unsigned& b) {
#if __has_builtin(__builtin_amdgcn_permlane16_swap)
    auto r = __builtin_amdgcn_permlane16_swap(a, b, false, false);
    a = r[0]; b = r[1];
#else
    asm volatile("v_permlane16_swap_b32 %0, %1" : "+v"(a), "+v"(b));
#endif
}

// Direct global->LDS DMA, 16B/lane. LDS dest = wave-uniform base + lane*16.
typedef __attribute__((address_space(1))) const unsigned int gu32;
typedef __attribute__((address_space(3))) unsigned int lu32;
__device__ __forceinline__ void gload16(const void* g, void* l) {
    __builtin_amdgcn_global_load_lds((gu32*)g, (lu32*)l, 16, 0, 0);
}

// ---------------------------------------------------------------------------
// prep: fp32->bf16 copies (y=0..5, scalar RNE cvt) + mask bit-pack (y=6),
// one launch. Mask job: 32768 independent wave-tasks, 4 loads in flight.
// (unchanged this round)
// ---------------------------------------------------------------------------
__global__ __launch_bounds__(256) void prep(
    const float* __restrict__ x,  const float* __restrict__ y,
    const float* __restrict__ wq, const float* __restrict__ wk,
    const float* __restrict__ wv, const float* __restrict__ wo,
    const float* __restrict__ mask,
    unsigned short* __restrict__ xb,  unsigned short* __restrict__ yb,
    unsigned short* __restrict__ wqb, unsigned short* __restrict__ wkb,
    unsigned short* __restrict__ wvb, unsigned short* __restrict__ wob,
    unsigned long long* __restrict__ mbits)
{
    if (blockIdx.y == 6) {
        const int wid = blockIdx.x * 4 + (threadIdx.x >> 6);   // 4096 waves
        const int lane = threadIdx.x & 63;
        for (int task = wid; task < BATCH * LQ * 8; task += 4096) {
            int row = task >> 3, g = task & 7;
            const float* mp = mask + (size_t)row * LK + g * 256;
            unsigned long long* ob = mbits + (size_t)row * (LK / 64) + g * 4;
            float v0 = mp[0 * 64 + lane];
            float v1 = mp[1 * 64 + lane];
            float v2 = mp[2 * 64 + lane];
            float v3 = mp[3 * 64 + lane];
            unsigned long long b0 = __ballot(v0 > 0.5f);
            unsigned long long b1 = __ballot(v1 > 0.5f);
            unsigned long long b2 = __ballot(v2 > 0.5f);
            unsigned long long b3 = __ballot(v3 > 0.5f);
            if (lane == 0) { ob[0] = b0; ob[1] = b1; ob[2] = b2; ob[3] = b3; }
        }
        return;
    }
    const float* src; unsigned short* dst; int n4;
    switch (blockIdx.y) {
        case 0: src = x;  dst = xb;  n4 = (BATCH * LQ * DIM) / 4; break;
        case 1: src = y;  dst = yb;  n4 = (BATCH * LK * DIM) / 4; break;
        case 2: src = wq; dst = wqb; n4 = (INNER * DIM) / 4; break;
        case 3: src = wk; dst = wkb; n4 = (INNER * DIM) / 4; break;
        case 4: src = wv; dst = wvb; n4 = (INNER * DIM) / 4; break;
        default: src = wo; dst = wob; n4 = (INNER * DIM) / 4; break;
    }
    const int stride = gridDim.x * 256;
    for (int i = blockIdx.x * 256 + threadIdx.x; i < n4; i += stride) {
        float4 f = ((const float4*)src)[i];
        ushort4 u;
        u.x = f2bf(f.x); u.y = f2bf(f.y); u.z = f2bf(f.z); u.w = f2bf(f.w);
        ((ushort4*)dst)[i] = u;
    }
}

// ---------------------------------------------------------------------------
// C = scale * (A[M,K] @ W[N,K]^T), bf16 in, fp32 accum.
// Tile = BM x BN with a WR x WC wave grid (per-wave tile IM*16 x JN*16),
// BK=64, THREADS = WR*WC*64. Swizzled global_load_lds staging
// (conflict-free b128 reads), double-buffered, one barrier/K-tile.
// This round: 128x128 tile, 8 waves (2x4) -> block arithmetic intensity 2x
// vs the old 128x64/4-wave config; same per-wave register footprint.
// EPI=0: row-major C. EPI=1: V-transpose epilogue into vt[b][h][d][key].
// SH layout: As = SH[0 .. 2*AUS), Bs = SH[2*AUS .. 2*AUS+2*BUS).
// ---------------------------------------------------------------------------
template <int IM, int JN, int WR, int WC, typename TC, int EPI>
__device__ __forceinline__ void gemm_body(
    const unsigned short* __restrict__ A,
    const unsigned short* __restrict__ W,
    TC* __restrict__ C,
    int K, int N, float scale,
    unsigned short* SH)
{
    constexpr int THREADS = WR * WC * 64;
    constexpr int BM = WR * IM * 16;
    constexpr int BN = WC * JN * 16;
    constexpr int ACH = BM * 8;     // 16B chunks per A tile
    constexpr int BCH = BN * 8;
    constexpr int AUS = BM * 64;    // shorts per A buffer
    constexpr int BUS = BN * 64;

    unsigned short* As = SH;
    unsigned short* Bs = SH + 2 * AUS;

    const int tid = threadIdx.x;
    const int m0 = blockIdx.x * BM;
    const int n0 = blockIdx.y * BN;
    const int w = tid >> 6, lane = tid & 63;
    const int q4 = lane >> 4, l16 = lane & 15;
    const int wm = (w / WC) * (IM * 16), wn = (w % WC) * (JN * 16);
    const int sw = l16 & 7;

    f32x4 acc[IM][JN] = {};

#pragma unroll
    for (int i = 0; i < ACH / THREADS; ++i) {
        int s = tid + i * THREADS;
        int r = s >> 3, ch = (s & 7) ^ (r & 7);
        gload16(A + (size_t)(m0 + r) * K + ch * 8, As + (size_t)s * 8);
    }
#pragma unroll
    for (int i = 0; i < BCH / THREADS; ++i) {
        int s = tid + i * THREADS;
        int r = s >> 3, ch = (s & 7) ^ (r & 7);
        gload16(W + (size_t)(n0 + r) * K + ch * 8, Bs + (size_t)s * 8);
    }
    __syncthreads();

    const int nt = K / 64;
    for (int t = 0; t < nt; ++t) {
        const int curA = (t & 1) * AUS;
        const int curB = (t & 1) * BUS;
        if (t + 1 < nt) {
            int kk = (t + 1) * 64;
            const int nxtA = AUS - curA, nxtB = BUS - curB;
#pragma unroll
            for (int i = 0; i < ACH / THREADS; ++i) {
                int s = tid + i * THREADS;
                int r = s >> 3, ch = (s & 7) ^ (r & 7);
                gload16(A + (size_t)(m0 + r) * K + kk + ch * 8, As + nxtA + (size_t)s * 8);
            }
#pragma unroll
            for (int i = 0; i < BCH / THREADS; ++i) {
                int s = tid + i * THREADS;
                int r = s >> 3, ch = (s & 7) ^ (r & 7);
                gload16(W + (size_t)(n0 + r) * K + kk + ch * 8, Bs + nxtB + (size_t)s * 8);
            }
        }

#pragma unroll
        for (int ks = 0; ks < 2; ++ks) {
            const int kq = ((ks * 4 + q4) ^ sw) * 8;
            short8 a[IM], b[JN];
#pragma unroll
            for (int i = 0; i < IM; ++i)
                a[i] = *(const short8*)(As + curA + (wm + i * 16 + l16) * 64 + kq);
#pragma unroll
            for (int j = 0; j < JN; ++j)
                b[j] = *(const short8*)(Bs + curB + (wn + j * 16 + l16) * 64 + kq);
#pragma unroll
            for (int i = 0; i < IM; ++i)
#pragma unroll
                for (int j = 0; j < JN; ++j)
                    acc[i][j] = __builtin_amdgcn_mfma_f32_16x16x32_bf16(
                        a[i], b[j], acc[i][j], 0, 0, 0);
        }
        __syncthreads();
    }

    if (EPI == 0) {
        // C/D layout: col = lane&15, row = quad*4 + reg  [m89-verified]
#pragma unroll
        for (int i = 0; i < IM; ++i)
#pragma unroll
            for (int j = 0; j < JN; ++j)
#pragma unroll
                for (int r = 0; r < 4; ++r) {
                    int row = m0 + wm + i * 16 + q4 * 4 + r;
                    int col = n0 + wn + j * 16 + l16;
                    stc(C, (size_t)row * N + col, acc[i][j][r] * scale);
                }
    } else {
        // V-transpose epilogue into vt[((b*H+h)*DH+d)*LK + key].
        // Per-wave TP region: DW x TPS shorts; WAVES * DW*TPS fits in SH
        // (all staging buffers dead after the loop's final barrier).
        constexpr int KW = IM * 16;
        constexpr int DW = JN * 16;
        constexpr int TPS = KW + 8;
        unsigned short* TP = SH + w * (DW * TPS);
#pragma unroll
        for (int i = 0; i < IM; ++i)
#pragma unroll
            for (int j = 0; j < JN; ++j) {
                ushort4 u;
                u.x = f2bf(acc[i][j][0]); u.y = f2bf(acc[i][j][1]);
                u.z = f2bf(acc[i][j][2]); u.w = f2bf(acc[i][j][3]);
                *(ushort4*)(TP + (j * 16 + l16) * TPS + i * 16 + q4 * 4) = u;
            }
        const int keyflat = m0 + wm;
        const int bb = keyflat >> 11, key0 = keyflat & (LK - 1);
        const int hh = (n0 + wn) >> 6;
        const int dlow = (n0 + wn) & 63;
        constexpr int RCH = KW / 8;
        constexpr int NCH = DW * RCH;
#pragma unroll
        for (int p = 0; p < NCH / 64; ++p) {
            int c = p * 64 + lane;
            int dl = c / RCH, kc = c % RCH;
            uint4 v = *(const uint4*)(TP + dl * TPS + kc * 8);
            *(uint4*)((unsigned short*)C +
                ((size_t)((bb * HEADS + hh) * DH + dlow + dl)) * LK + key0 + kc * 8) = v;
        }
    }
}

// q scaled by 0.125*log2(e) so attn uses raw v_exp_f32 (2^x) directly.
#define QSCALE 0.18033688011112042f

__global__ __launch_bounds__(512) void proj_qkv(
    const unsigned short* __restrict__ xb, const unsigned short* __restrict__ yb,
    const unsigned short* __restrict__ wqb, const unsigned short* __restrict__ wkb,
    const unsigned short* __restrict__ wvb,
    unsigned short* __restrict__ qb, unsigned short* __restrict__ kb,
    unsigned short* __restrict__ vt)
{
    __shared__ __align__(16) unsigned short SH[4 * 128 * 64];  // 64 KB
    const int z = blockIdx.z;
    const unsigned short* A = (z == 0) ? xb : yb;
    const unsigned short* W = (z == 0) ? wqb : (z == 1) ? wkb : wvb;
    if (z == 2)
        gemm_body<4, 2, 2, 4, unsigned short, 1>(A, W, vt, DIM, INNER, 1.0f, SH);
    else
        gemm_body<4, 2, 2, 4, unsigned short, 0>(A, W, (z == 0) ? qb : kb, DIM, INNER,
                                                 (z == 0) ? QSCALE : 1.0f, SH);
}

__global__ __launch_bounds__(512) void gemm_out(
    const unsigned short* __restrict__ A,
    const unsigned short* __restrict__ W,
    float* __restrict__ C)
{
    __shared__ __align__(16) unsigned short SH[4 * 128 * 64];  // 64 KB
    gemm_body<4, 2, 2, 4, float, 0>(A, W, C, INNER, DIM, 1.0f, SH);
}

// ---------------------------------------------------------------------------
// Flash attention v3: in-register P path (T12 swapped-operand softmax).
// (unchanged this round)
// S^T = mfma(K, Q): lane(q4,l16) holds P[key=16j+4*q4+r][q=l16]. PV is
// O^T = mfma(V^T, P^T); V^T is exactly what vt stages, so vf reads are
// unchanged. P^T B-frag built in-register: 8x v_cvt_pk_bf16_f32 + per-ks
// {permlane32_swap; permlane16_swap} on (w[j0],w[j1]) pairs.
// LDS = 32K (K) + 32K (V) = 65536 B.
// ---------------------------------------------------------------------------
#define AT_SLOT (64 * 64)

__global__ __launch_bounds__(512, 4) void attn_mfma(
    const unsigned short* __restrict__ Q,
    const unsigned short* __restrict__ Kb,
    const unsigned short* __restrict__ Vt,
    const unsigned long long* __restrict__ Mb,
    unsigned short* __restrict__ O)
{
    __shared__ __align__(16) unsigned short Ks[4 * AT_SLOT];   // 32 KB
    __shared__ __align__(16) unsigned short Vs[4 * AT_SLOT];   // 32 KB

    const int tid = threadIdx.x;
    const int q0 = blockIdx.x * 64;
    const int h = blockIdx.y, b = blockIdx.z;
    const int w = tid >> 6, lane = tid & 63;
    const int g = w & 3;           // q-row group (16 rows)
    const int par = w >> 2;        // key-tile parity this wave computes
    const int q4 = lane >> 4, l16 = lane & 15;
    const int sw = l16 & 7;

    // Q as B-operand fragment: col q = l16, k-chunk = q4
    short8 qf[2];
    {
        const unsigned short* qp =
            Q + (size_t)(b * LQ + q0 + g * 16 + l16) * INNER + h * DH + q4 * 8;
        qf[0] = *(const short8*)(qp);
        qf[1] = *(const short8*)(qp + 32);
    }

    f32x4 o[4] = {};
    float lacc = 0.f;

    const unsigned short* kbase = Kb + (size_t)(b * LK) * INNER + h * DH;
    const unsigned short* vbase = Vt + (size_t)((b * HEADS + h) * DH) * LK;
    // one mask row per lane now: q = l16
    const unsigned long long* mrow =
        Mb + (size_t)(b * LQ + q0 + g * 16 + l16) * (LK / 64);

    // per-thread staging coords: 512 threads stage one 64x64 tile per gload16
    const int rr = tid >> 3;
    const int ch = (tid & 7) ^ (rr & 7);

    // prologue: tiles 0,1 -> slots 0,1
#pragma unroll
    for (int tn = 0; tn < 2; ++tn) {
        gload16(kbase + (size_t)(tn * 64 + rr) * INNER + ch * 8,
                Ks + tn * AT_SLOT + (size_t)tid * 8);
        gload16(vbase + (size_t)rr * LK + tn * 64 + ch * 8,
                Vs + tn * AT_SLOT + (size_t)tid * 8);
    }
    __syncthreads();

    const int NR = LK / 128;   // 16 rounds, 2 tiles each
    for (int rd = 0; rd < NR; ++rd) {
        if (rd + 1 < NR) {
#pragma unroll
            for (int i = 0; i < 2; ++i) {
                const int tn = 2 * rd + 2 + i;
                const int sl = tn & 3;
                gload16(kbase + (size_t)(tn * 64 + rr) * INNER + ch * 8,
                        Ks + sl * AT_SLOT + (size_t)tid * 8);
                gload16(vbase + (size_t)rr * LK + tn * 64 + ch * 8,
                        Vs + sl * AT_SLOT + (size_t)tid * 8);
            }
        }
        const int t = 2 * rd + par;
        const int cur = (t & 3) * AT_SLOT;

        // ---- S^T = K Q^T (A = K rows, B = Q) ----
        f32x4 s[4];
#pragma unroll
        for (int j = 0; j < 4; ++j) {
            s[j] = f32x4{0.f, 0.f, 0.f, 0.f};
#pragma unroll
            for (int ks = 0; ks < 2; ++ks) {
                short8 kf = *(const short8*)(Ks + cur + (j * 16 + l16) * 64
                                             + (((ks * 4 + q4) ^ sw) * 8));
                s[j] = __builtin_amdgcn_mfma_f32_16x16x32_bf16(kf, qf[ks], s[j], 0, 0, 0);
            }
        }

        // ---- p = masked ? 0 : 2^s ; pack to bf16 pairs in-register ----
        // lane needs key bits {16j + 4*q4 + r}: shift out 4*q4, then nibbles.
        unsigned long long bsh = mrow[t] >> (q4 * 4);
        unsigned pk[8];
#pragma unroll
        for (int j = 0; j < 4; ++j) {
            unsigned nib = (unsigned)(bsh >> (16 * j)) & 0xFu;
            float p0 = (nib & 1u) ? 0.f : fexp2(s[j][0]);
            float p1 = (nib & 2u) ? 0.f : fexp2(s[j][1]);
            float p2 = (nib & 4u) ? 0.f : fexp2(s[j][2]);
            float p3 = (nib & 8u) ? 0.f : fexp2(s[j][3]);
            lacc += (p0 + p1) + (p2 + p3);
            pk[2 * j]     = cvtpk_bf16(p0, p1);
            pk[2 * j + 1] = cvtpk_bf16(p2, p3);
        }

        // ---- P^T B-frag via permlane (no LDS) ----
        short8 pf[2];
#pragma unroll
        for (int ks = 0; ks < 2; ++ks) {
            unsigned a0 = pk[4 * ks + 0], b0 = pk[4 * ks + 2];  // w0[j0], w0[j1]
            unsigned a1 = pk[4 * ks + 1], b1 = pk[4 * ks + 3];  // w1[j0], w1[j1]
            perm32swap(a0, b0); perm16swap(a0, b0);  // a0 = keys{0,1}, b0 = keys{4,5}
            perm32swap(a1, b1); perm16swap(a1, b1);  // a1 = keys{2,3}, b1 = keys{6,7}
            union { unsigned u[4]; short8 s8; } up;
            up.u[0] = a0; up.u[1] = a1; up.u[2] = b0; up.u[3] = b1;
            pf[ks] = up.s8;
        }

        // ---- O^T += V^T P^T (vf reads unchanged) ----
#pragma unroll
        for (int ks = 0; ks < 2; ++ks) {
#pragma unroll
            for (int dd = 0; dd < 4; ++dd) {
                short8 vf = *(const short8*)(Vs + cur + (dd * 16 + l16) * 64
                                             + (((ks * 4 + q4) ^ sw) * 8));
                o[dd] = __builtin_amdgcn_mfma_f32_16x16x32_bf16(vf, pf[ks], o[dd], 0, 0, 0);
            }
        }
        __syncthreads();
    }

    // ---- parity combine (exact: no-max softmax partial sums add) ----
    // Ks is dead; reuse as f32 exchange. 17 floats/lane, odd stride => 2-way.
    float* xch = (float*)Ks;
    if (par) {
        float* d = xch + (size_t)(g * 64 + lane) * 17;
#pragma unroll
        for (int dd = 0; dd < 4; ++dd)
#pragma unroll
            for (int r2 = 0; r2 < 4; ++r2) d[dd * 4 + r2] = o[dd][r2];
        d[16] = lacc;
    }
    __syncthreads();
    if (!par) {
        const float* d = xch + (size_t)(g * 64 + lane) * 17;
#pragma unroll
        for (int dd = 0; dd < 4; ++dd)
#pragma unroll
            for (int r2 = 0; r2 < 4; ++r2) o[dd][r2] += d[dd * 4 + r2];
        lacc += d[16];

        // reduce l across the 4 q4 groups (keys were split across q4)
        lacc += __shfl_xor(lacc, 16);
        lacc += __shfl_xor(lacc, 32);
        const float inv = 1.0f / lacc;

        // O^T layout: q = l16 (one row per lane), d = dd*16 + q4*4 + r
        unsigned short* orow =
            O + (size_t)(b * LQ + q0 + g * 16 + l16) * INNER + h * DH + q4 * 4;
#pragma unroll
        for (int dd = 0; dd < 4; ++dd) {
            ushort4 u;
            u.x = f2bf(o[dd][0] * inv); u.y = f2bf(o[dd][1] * inv);
            u.z = f2bf(o[dd][2] * inv); u.w = f2bf(o[dd][3] * inv);
            *(ushort4*)(orow + dd * 16) = u;
        }
    }
}

extern "C" void kernel_launch(void* const* d_in, const int* in_sizes, int n_in,
                              void* d_out, int out_size, void* d_ws, size_t ws_size,
                              hipStream_t stream) {
    const float* x    = (const float*)d_in[0];
    const float* y    = (const float*)d_in[1];
    const float* mask = (const float*)d_in[2];
    const float* Wq   = (const float*)d_in[3];
    const float* Wk   = (const float*)d_in[4];
    const float* Wv   = (const float*)d_in[5];
    const float* Wo   = (const float*)d_in[6];
    float* out = (float*)d_out;

    const size_t NX = (size_t)BATCH * LQ * DIM;    // 4.19M
    const size_t NS = (size_t)BATCH * LQ * INNER;  // 2.10M
    const size_t NW = (size_t)INNER * DIM;         // 0.52M
    unsigned short* xb  = (unsigned short*)d_ws;
    unsigned short* yb  = xb + NX;
    unsigned short* qb  = yb + NX;
    unsigned short* kb  = qb + NS;
    unsigned short* vt  = kb + NS;
    unsigned short* wqb = vt + NS;
    unsigned short* wkb = wqb + NW;
    unsigned short* wvb = wkb + NW;
    unsigned short* wob = wvb + NW;
    unsigned long long* mbits = (unsigned long long*)(wob + NW);
    unsigned short* ao  = xb;   // xb dead after proj
    // ws: 33.8 MB bf16 + 1 MB bits

    dim3 blk(256);
    prep<<<dim3(1024, 7), blk, 0, stream>>>(
        x, y, Wq, Wk, Wv, Wo, mask, xb, yb, wqb, wkb, wvb, wob, mbits);
    proj_qkv<<<dim3(4096 / 128, INNER / 128, 3), dim3(512), 0, stream>>>(
        xb, yb, wqb, wkb, wvb, qb, kb, vt);
    attn_mfma<<<dim3(LQ / 64, HEADS, BATCH), dim3(512), 0, stream>>>(
        qb, kb, vt, mbits, ao);
    gemm_out<<<dim3(4096 / 128, DIM / 128), dim3(512), 0, stream>>>(ao, wob, out);
}